// Round 16
// baseline (405.795 us; speedup 1.0000x reference)
//
#include <hip/hip_runtime.h>

#define HID 128
#define NBUCK 512          // 2^9 buckets, 256 nodes each
#define BSHIFT 8
#define NB 512             // chunk blocks per pipeline
#define M4 (4 * NBUCK * NB)
#define STAGE_CAP 8192     // real edges per bucket: mean 4096, +64 sigma
#define PCAP 7168          // padded csr slots per bucket: mean 5888, +10 sigma

typedef __attribute__((ext_vector_type(8))) short bf16x8;
typedef __attribute__((ext_vector_type(4))) float f32x4;

__device__ __forceinline__ unsigned short f2bf(float f) {   // RNE
    union { float f; unsigned u; } v; v.f = f;
    unsigned r = v.u + 0x7fff + ((v.u >> 16) & 1);
    return (unsigned short)(r >> 16);
}
__device__ __forceinline__ float bf2f(unsigned short b) {
    union { float f; unsigned u; } v; v.u = ((unsigned)b) << 16;
    return v.f;
}

// ---------------------------------------------------------------- P1: all 4 pipes, per-(bucket, block) counts
__global__ __launch_bounds__(256) void bucket_count_all(
    const int* __restrict__ k0, const int* __restrict__ k1,
    const int* __restrict__ k2, const int* __restrict__ k3,
    int* __restrict__ counts, int E, int chunk) {
    __shared__ int h[4][NBUCK];
    int tid = threadIdx.x;
    #pragma unroll
    for (int j = 0; j < 8; ++j) ((int*)h)[tid + j * 256] = 0;
    __syncthreads();
    int base = blockIdx.x * chunk;
    int end = min(base + chunk, E);
    const int* keys[4] = {k0, k1, k2, k3};
    #pragma unroll
    for (int p = 0; p < 4; ++p) {
        const int* kp = keys[p];
        for (int i = base + tid; i < end; i += 256)
            atomicAdd(&h[p][kp[i] >> BSHIFT], 1);
    }
    __syncthreads();
    #pragma unroll
    for (int p = 0; p < 4; ++p) {
        counts[((p << 9) + tid) * NB + blockIdx.x] = h[p][tid];
        counts[((p << 9) + tid + 256) * NB + blockIdx.x] = h[p][tid + 256];
    }
}

// ---------------------------------------------------------------- scan (2 kernels; scan_c folded into consumers)
__global__ __launch_bounds__(256) void scan_a(int* __restrict__ data, int* __restrict__ partials, int m) {
    __shared__ int sdata[256];
    int base = blockIdx.x * 1024;
    int tid = threadIdx.x;
    int v[4]; int s = 0;
    #pragma unroll
    for (int i = 0; i < 4; ++i) { int idx = base + tid * 4 + i; v[i] = (idx < m) ? data[idx] : 0; s += v[i]; }
    sdata[tid] = s; __syncthreads();
    for (int off = 1; off < 256; off <<= 1) {
        int t = (tid >= off) ? sdata[tid - off] : 0; __syncthreads();
        sdata[tid] += t; __syncthreads();
    }
    int excl = sdata[tid] - s;
    if (tid == 255) partials[blockIdx.x] = sdata[255];
    int run = excl;
    #pragma unroll
    for (int i = 0; i < 4; ++i) { int idx = base + tid * 4 + i; if (idx < m) data[idx] = run; run += v[i]; }
}

__global__ __launch_bounds__(1024) void scan_b(int* __restrict__ partials, int nb) {
    __shared__ int sdata[1024];
    int tid = threadIdx.x;
    int v = (tid < nb) ? partials[tid] : 0;
    sdata[tid] = v; __syncthreads();
    for (int off = 1; off < 1024; off <<= 1) {
        int t = (tid >= off) ? sdata[tid - off] : 0; __syncthreads();
        sdata[tid] += t; __syncthreads();
    }
    if (tid < nb) partials[tid] = sdata[tid] - v;
}

// ---------------------------------------------------------------- P3: all 4 pipes, scatter into buckets (adds partials on the fly)
__global__ __launch_bounds__(256) void bucket_scatter_all(
    const int* __restrict__ k0, const int* __restrict__ k1,
    const int* __restrict__ k2, const int* __restrict__ k3,
    const int* __restrict__ pay0, const int* __restrict__ pay1,
    const int* __restrict__ scanned, const int* __restrict__ partials,
    unsigned* __restrict__ bucketed, int E, int chunk) {
    __shared__ unsigned cur[4][NBUCK];
    int tid = threadIdx.x;
    int blk = blockIdx.x;
    #pragma unroll
    for (int p = 0; p < 4; ++p) {
        int i0 = ((p << 9) + tid) * NB + blk;
        int i1 = ((p << 9) + tid + 256) * NB + blk;
        cur[p][tid]       = (unsigned)(scanned[i0] + partials[i0 >> 10]);
        cur[p][tid + 256] = (unsigned)(scanned[i1] + partials[i1 >> 10]);
    }
    __syncthreads();
    int base = blk * chunk;
    int end = min(base + chunk, E);
    const int* keys[4] = {k0, k1, k2, k3};
    const int* pays[4] = {pay0, pay1, nullptr, nullptr};
    #pragma unroll
    for (int p = 0; p < 4; ++p) {
        const int* kp = keys[p];
        const int* pp = pays[p];
        for (int i = base + tid; i < end; i += 256) {
            int k = kp[i];
            int b = k >> BSHIFT;
            unsigned pay = pp ? (unsigned)pp[i] : 0u;
            unsigned pos = atomicAdd(&cur[p][b], 1u);
            bucketed[pos] = ((unsigned)(k & 255) << 17) | pay;
        }
    }
}

// ---------------------------------------------------------------- P4: per bucket: degrees; dst pipes write PADDED csr (pad -> zero row n)
__global__ __launch_bounds__(256) void bucket_finalize(
    const unsigned* __restrict__ bucketed, const int* __restrict__ scanned,
    const int* __restrict__ partials,
    int* __restrict__ prow0, int* __restrict__ prow1,
    int* __restrict__ din0, int* __restrict__ din1,
    int* __restrict__ dout0, int* __restrict__ dout1,
    int* __restrict__ csr0, int* __restrict__ csr1, int n, int E) {
    __shared__ unsigned stage[STAGE_CAP];
    __shared__ int cnt[256];
    __shared__ int sd[256];
    __shared__ int pexcl[256];
    __shared__ int cur[256];
    int tid = threadIdx.x;
    int g = blockIdx.x;
    int p = g >> 9;
    int b = g & 511;
    int i0 = g * NB;
    int start = scanned[i0] + partials[i0 >> 10];
    int end;
    if (g == 4 * NBUCK - 1) end = 4 * E;
    else { int i1 = (g + 1) * NB; end = scanned[i1] + partials[i1 >> 10]; }
    if (end - start > STAGE_CAP) end = start + STAGE_CAP;
    int len = end - start;
    int node0 = b << BSHIFT;

    cnt[tid] = 0;
    __syncthreads();
    if (p < 2) {
        for (int i = tid; i < len; i += 256) {
            unsigned v = bucketed[start + i];
            stage[i] = v;
            atomicAdd(&cnt[v >> 17], 1);
        }
    } else {
        for (int i = tid; i < len; i += 256)
            atomicAdd(&cnt[bucketed[start + i] >> 17], 1);
    }
    __syncthreads();

    if (p >= 2) {                   // src-keyed: out-degrees only
        int* dout = (p == 2) ? dout0 : dout1;
        int node = node0 + tid;
        if (node < n) dout[node] = cnt[tid];
        return;
    }

    // dst-keyed: padded exclusive scan of ceil(cnt/16)*16
    int c = cnt[tid];
    int pc = (c + 15) & ~15;
    sd[tid] = pc;
    __syncthreads();
    for (int off = 1; off < 256; off <<= 1) {
        int t = (tid >= off) ? sd[tid - off] : 0; __syncthreads();
        sd[tid] += t; __syncthreads();
    }
    pexcl[tid] = sd[tid] - pc;
    cur[tid] = 0;
    __syncthreads();
    int ptot = sd[255];
    if (ptot > PCAP) ptot = PCAP;   // unreachable (+10 sigma)

    int* csr  = (p == 0) ? csr0  : csr1;
    int* prow = (p == 0) ? prow0 : prow1;
    int* din  = (p == 0) ? din0  : din1;
    int node = node0 + tid;
    if (node < n) { prow[node] = b * PCAP + pexcl[tid]; din[node] = c; }

    const int base = b * PCAP;
    for (int j = tid; j < ptot; j += 256) csr[base + j] = n;   // pad = zero row
    __syncthreads();
    for (int i = tid; i < len; i += 256) {
        unsigned w = stage[i];
        int nl = (int)(w >> 17);
        int pos = base + pexcl[nl] + atomicAdd(&cur[nl], 1);
        csr[pos] = (int)(w & 0x1FFFFu);
    }
}

// ---------------------------------------------------------------- swizzled B-fragment index for mfma_f32_16x16x32_bf16
__device__ __forceinline__ size_t bswz_idx(int k, int col) {
    int s = k >> 5, lh = (k >> 3) & 3, j = k & 7;
    int c = col >> 4, lc = col & 15;
    return ((((size_t)s * 8 + c) * 64 + (lh * 16 + lc)) * 8 + j);
}

// ---------------------------------------------------------------- weight_prep: blocks 0..128 = M=We@W1 fuse (+bias row);
// blocks 129..192 = swizzle_split of W2. One dispatch for all weight prep.
__global__ __launch_bounds__(256) void weight_prep(
    const float* __restrict__ We, const float* __restrict__ be,
    const float* __restrict__ W1, const float* __restrict__ W2,
    unsigned short* __restrict__ B1h, unsigned short* __restrict__ B1l,
    unsigned short* __restrict__ B2h, unsigned short* __restrict__ B2l,
    float* __restrict__ cv) {
    int tid = threadIdx.x;
    if (blockIdx.x >= 129) {
        int idx = (blockIdx.x - 129) * 256 + tid;
        if (idx >= 128 * 128) return;
        int k = idx >> 7, col = idx & 127;
        float v = W2[idx];
        unsigned short h = f2bf(v);
        unsigned short l = f2bf(v - bf2f(h));
        size_t o = bswz_idx(k, col);
        B2h[o] = h; B2l[o] = l;
        return;
    }
    __shared__ float w1[128][128];
    #pragma unroll
    for (int it = 0; it < 16; ++it) {
        int s = tid + it * 256;
        int r = s >> 5, c4 = (s & 31) << 2;
        *(float4*)&w1[r][c4] = *(const float4*)&W1[r * 128 + c4];
    }
    __syncthreads();
    int j = tid & 127;
    int half = tid >> 7;
    if (blockIdx.x == 128) {
        if (half) return;
        float sum = 0.f;
        for (int k = 0; k < 128; ++k) sum += be[k] * w1[k][j];
        cv[j] = sum;
        return;
    }
    int i = blockIdx.x * 2 + half;
    const float* arow = &We[i * 128];
    float sum = 0.f;
    for (int k = 0; k < 128; ++k) sum += arow[k] * w1[k][j];
    unsigned short h = f2bf(sum);
    unsigned short l = f2bf(sum - bf2f(h));
    size_t o = bswz_idx(i, j);
    B1h[o] = h; B1l[o] = l;
}

// ---------------------------------------------------------------- MFMA GEMM, B-stationary in registers, ZERO barriers, no LDS.
// Block = 8 waves; wave w owns col-tile c=w (16 cols), holding its B strip
// (hi+lo, all K) in 64 (K=256) / 32 (K=128) VGPRs, loaded once. All 8 waves
// sweep the SAME 16-row A tiles (grid-stride) -> wave 0's A fetch makes rows
// L2-hot for the rest; waves run completely free (no syncs at all).
template <int K, bool AFP32>
__global__ __launch_bounds__(512) void gemm_breg(
    const void* __restrict__ X_,
    const unsigned short* __restrict__ Bh, const unsigned short* __restrict__ Bl,
    const float* __restrict__ cvec, const int* __restrict__ degs,
    unsigned short* __restrict__ T, int n) {
    constexpr int NS = K / 32;
    const int tid = threadIdx.x;
    const int wave = tid >> 6;
    const int lane = tid & 63;
    const int lr = lane & 15;
    const int lk = lane >> 4;
    const int c = wave;                 // col tile 0..7

    const bf16x8* pBh = (const bf16x8*)Bh;
    const bf16x8* pBl = (const bf16x8*)Bl;
    bf16x8 rbh[NS], rbl[NS];
    #pragma unroll
    for (int s = 0; s < NS; ++s) {
        rbh[s] = pBh[s * 512 + c * 64 + lane];
        rbl[s] = pBl[s * 512 + c * 64 + lane];
    }

    const int tiles = (n + 15) >> 4;
    for (int rt = blockIdx.x; rt < tiles; rt += gridDim.x) {
        const int row0 = rt << 4;
        const int grow = row0 + lr;
        const int growc = (grow < n) ? grow : (n - 1);
        const float* pxf = (const float*)X_ + (size_t)growc * K + lk * 8;
        const unsigned short* pxb = (const unsigned short*)X_ + (size_t)growc * K + lk * 8;

        f32x4 acc = (f32x4)0.f;
        float4 a0 = make_float4(0.f, 0.f, 0.f, 0.f), a1 = a0;
        bf16x8 ab = (bf16x8)0;
        if (AFP32) { a0 = *(const float4*)pxf; a1 = *(const float4*)(pxf + 4); }
        else       { ab = *(const bf16x8*)pxb; }

        #pragma unroll
        for (int s = 0; s < NS; ++s) {
            // prefetch A for s+1 (in flight under this step's MFMAs)
            float4 n0 = make_float4(0.f, 0.f, 0.f, 0.f), n1 = n0;
            bf16x8 nb = (bf16x8)0;
            if (s + 1 < NS) {
                if (AFP32) {
                    n0 = *(const float4*)(pxf + (s + 1) * 32);
                    n1 = *(const float4*)(pxf + (s + 1) * 32 + 4);
                } else {
                    nb = *(const bf16x8*)(pxb + (s + 1) * 32);
                }
            }

            bf16x8 ah, al;
            if (AFP32) {
                float av[8] = {a0.x, a0.y, a0.z, a0.w, a1.x, a1.y, a1.z, a1.w};
                #pragma unroll
                for (int j = 0; j < 8; ++j) {
                    unsigned short h = f2bf(av[j]);
                    ah[j] = (short)h;
                    al[j] = (short)f2bf(av[j] - bf2f(h));
                }
            } else {
                ah = ab;
            }

            acc = __builtin_amdgcn_mfma_f32_16x16x32_bf16(ah, rbh[s], acc, 0, 0, 0);
            acc = __builtin_amdgcn_mfma_f32_16x16x32_bf16(ah, rbl[s], acc, 0, 0, 0);
            if (AFP32)
                acc = __builtin_amdgcn_mfma_f32_16x16x32_bf16(al, rbh[s], acc, 0, 0, 0);

            a0 = n0; a1 = n1; ab = nb;
        }

        // C/D: col = lane&15 (=lr), row = lk*4 + r
        #pragma unroll
        for (int r = 0; r < 4; ++r) {
            int orow = row0 + lk * 4 + r;
            if (orow >= n) continue;
            float norm = rsqrtf(fmaxf((float)degs[orow], 1.0f));
            float v = acc[r];
            if (cvec) v += cvec[c * 16 + lr];
            T[(size_t)orow * 128 + c * 16 + lr] = f2bf(v * norm);
        }
    }
}

// ---------------------------------------------------------------- aggregate: padded CSR, zero tail -> always 8 gathers in flight
template <bool OUT_BF16>
__global__ __launch_bounds__(256) void aggregate(
    const unsigned short* __restrict__ T, const int* __restrict__ prow,
    const int* __restrict__ din, const int* __restrict__ csr,
    const float* __restrict__ bias, void* __restrict__ out_, int n) {
    const int wave = threadIdx.x >> 6;
    const int lane = threadIdx.x & 63;
    const int half = lane >> 5;
    const int l32 = lane & 31;
    const int node = blockIdx.x * 4 + wave;
    if (node >= n) return;
    const int beg = prow[node];
    const int d = din[node];
    const int plen = (d + 15) & ~15;
    float a0 = 0.f, a1 = 0.f, a2 = 0.f, a3 = 0.f;
    for (int e = beg; e < beg + plen; e += 16) {
        int sidx[8];
        #pragma unroll
        for (int j = 0; j < 8; ++j) sidx[j] = csr[e + j * 2 + half];
        #pragma unroll
        for (int j = 0; j < 8; ++j) {
            uint2 u = *(const uint2*)&T[(size_t)sidx[j] * 128 + l32 * 4];
            a0 += __uint_as_float(u.x << 16);
            a1 += __uint_as_float(u.x & 0xffff0000u);
            a2 += __uint_as_float(u.y << 16);
            a3 += __uint_as_float(u.y & 0xffff0000u);
        }
    }
    a0 += __shfl_xor(a0, 32);
    a1 += __shfl_xor(a1, 32);
    a2 += __shfl_xor(a2, 32);
    a3 += __shfl_xor(a3, 32);
    if (half == 0) {
        float norm = rsqrtf(fmaxf((float)d, 1.0f));
        float4 bv = *(const float4*)&bias[l32 * 4];
        float o0 = fmaxf(a0 * norm + bv.x, 0.f);
        float o1 = fmaxf(a1 * norm + bv.y, 0.f);
        float o2 = fmaxf(a2 * norm + bv.z, 0.f);
        float o3 = fmaxf(a3 * norm + bv.w, 0.f);
        if (OUT_BF16) {
            unsigned w0 = (unsigned)f2bf(o0) | ((unsigned)f2bf(o1) << 16);
            unsigned w1 = (unsigned)f2bf(o2) | ((unsigned)f2bf(o3) << 16);
            uint2* dst = (uint2*)((unsigned short*)out_ + (size_t)node * 128 + l32 * 4);
            *dst = make_uint2(w0, w1);
        } else {
            float4* dst = (float4*)((float*)out_ + (size_t)node * 128 + l32 * 4);
            *dst = make_float4(o0, o1, o2, o3);
        }
    }
}

// ---------------------------------------------------------------- launch
extern "C" void kernel_launch(void* const* d_in, const int* in_sizes, int n_in,
                              void* d_out, int out_size, void* d_ws, size_t ws_size,
                              hipStream_t stream) {
    const float* x   = (const float*)d_in[0];
    const float* We  = (const float*)d_in[1];
    const float* be  = (const float*)d_in[2];
    const float* W1  = (const float*)d_in[3];
    const float* b1  = (const float*)d_in[4];
    const float* W2  = (const float*)d_in[5];
    const float* b2  = (const float*)d_in[6];
    const int* src0  = (const int*)d_in[7];
    const int* dst0  = (const int*)d_in[8];
    const int* src1  = (const int*)d_in[9];
    const int* dst1  = (const int*)d_in[10];
    float* out = (float*)d_out;

    const int n = in_sizes[0] / 256;   // 100000
    const int E = in_sizes[7];         // 1600000
    const int chunk = (E + NB - 1) / NB;

    char* p = (char*)d_ws;
    auto carve = [&](size_t bytes) -> void* {
        void* r = (void*)p;
        p += (bytes + 511) & ~(size_t)511;
        return r;
    };
    unsigned short* t        = (unsigned short*)carve(((size_t)n + 1) * HID * 2);  // [(n+1)][128] bf16, row n = zeros
    unsigned*       bucketed = (unsigned*)carve((size_t)4 * E * 4);                // dead after finalize -> h1 overlay
    int*            counts   = (int*)carve((size_t)M4 * 4);
    int*            partials = (int*)carve(1024 * 4);
    int*            csr0     = (int*)carve((size_t)NBUCK * PCAP * 4);   // 14.7 MB
    int*            csr1     = (int*)carve((size_t)NBUCK * PCAP * 4);
    int*            prow0    = (int*)carve((size_t)n * 4);
    int*            prow1    = (int*)carve((size_t)n * 4);
    int*            din0     = (int*)carve((size_t)n * 4);
    int*            din1     = (int*)carve((size_t)n * 4);
    int*            dout0    = (int*)carve((size_t)n * 4);
    int*            dout1    = (int*)carve((size_t)n * 4);
    unsigned short* B1h      = (unsigned short*)carve(256 * HID * 2);
    unsigned short* B1l      = (unsigned short*)carve(256 * HID * 2);
    unsigned short* B2h      = (unsigned short*)carve(128 * HID * 2);
    unsigned short* B2l      = (unsigned short*)carve(128 * HID * 2);
    float*          cv       = (float*)carve(HID * 4);

    unsigned short* h1 = (unsigned short*)bucketed;   // bucketed dead after finalize; exact 25.6 MB fit

    const int gGemm  = 1024;                 // grid-stride over 6250 row-tiles
    const int gAggN  = (n + 3) / 4;
    const int gScanA = (M4 + 1023) / 1024;   // 1024

    // zero pad-row of t (gathers for padded csr entries land here, stays L2-hot)
    hipMemsetAsync(t + (size_t)n * HID, 0, HID * 2, stream);

    // --- graph build (zero global atomics) ---
    bucket_count_all<<<NB, 256, 0, stream>>>(dst0, dst1, src0, src1, counts, E, chunk);
    scan_a<<<gScanA, 256, 0, stream>>>(counts, partials, M4);
    scan_b<<<1, 1024, 0, stream>>>(partials, gScanA);
    bucket_scatter_all<<<NB, 256, 0, stream>>>(dst0, dst1, src0, src1, src0, src1,
                                               counts, partials, bucketed, E, chunk);
    bucket_finalize<<<4 * NBUCK, 256, 0, stream>>>(bucketed, counts, partials, prow0, prow1,
                                                   din0, din1, dout0, dout1, csr0, csr1, n, E);

    // --- weights (single dispatch) ---
    weight_prep<<<193, 256, 0, stream>>>(We, be, W1, W2, B1h, B1l, B2h, B2l, cv);

    // --- network ---
    gemm_breg<256, true><<<gGemm, 512, 0, stream>>>((const void*)x, B1h, B1l, cv, dout0, t, n);
    aggregate<true><<<gAggN, 256, 0, stream>>>(t, prow0, din0, csr0, b1, (void*)h1, n);
    gemm_breg<128, false><<<gGemm, 512, 0, stream>>>((const void*)h1, B2h, B2l, nullptr, dout1, t, n);
    aggregate<false><<<gAggN, 256, 0, stream>>>(t, prow1, din1, csr1, b2, (void*)out, n);
}

// Round 17
// 299.878 us; speedup vs baseline: 1.3532x; 1.3532x over previous
//
#include <hip/hip_runtime.h>

#define HID 128
#define NBUCK 512          // 2^9 buckets, 256 nodes each
#define BSHIFT 8
#define NB 512             // chunk blocks per pipeline
#define M4 (4 * NBUCK * NB)
#define STAGE_CAP 8192     // real edges per bucket: mean 4096, +64 sigma
#define PCAP 7168          // padded csr slots per bucket: mean 5888, +10 sigma

typedef __attribute__((ext_vector_type(8))) short bf16x8;
typedef __attribute__((ext_vector_type(4))) float f32x4;

__device__ __forceinline__ unsigned short f2bf(float f) {   // RNE
    union { float f; unsigned u; } v; v.f = f;
    unsigned r = v.u + 0x7fff + ((v.u >> 16) & 1);
    return (unsigned short)(r >> 16);
}
__device__ __forceinline__ float bf2f(unsigned short b) {
    union { float f; unsigned u; } v; v.u = ((unsigned)b) << 16;
    return v.f;
}

// async global->LDS, 16B per lane (global_load_lds_dwordx4)
__device__ __forceinline__ void gload_lds16(const void* g, void* l) {
    __builtin_amdgcn_global_load_lds(
        (const __attribute__((address_space(1))) void*)g,
        (__attribute__((address_space(3))) void*)l, 16, 0, 0);
}

// ---------------------------------------------------------------- P1: all 4 pipes, per-(bucket, block) counts
__global__ __launch_bounds__(256) void bucket_count_all(
    const int* __restrict__ k0, const int* __restrict__ k1,
    const int* __restrict__ k2, const int* __restrict__ k3,
    int* __restrict__ counts, int E, int chunk) {
    __shared__ int h[4][NBUCK];
    int tid = threadIdx.x;
    #pragma unroll
    for (int j = 0; j < 8; ++j) ((int*)h)[tid + j * 256] = 0;
    __syncthreads();
    int base = blockIdx.x * chunk;
    int end = min(base + chunk, E);
    const int* keys[4] = {k0, k1, k2, k3};
    #pragma unroll
    for (int p = 0; p < 4; ++p) {
        const int* kp = keys[p];
        for (int i = base + tid; i < end; i += 256)
            atomicAdd(&h[p][kp[i] >> BSHIFT], 1);
    }
    __syncthreads();
    #pragma unroll
    for (int p = 0; p < 4; ++p) {
        counts[((p << 9) + tid) * NB + blockIdx.x] = h[p][tid];
        counts[((p << 9) + tid + 256) * NB + blockIdx.x] = h[p][tid + 256];
    }
}

// ---------------------------------------------------------------- scan (2 kernels; scan_c folded into consumers)
__global__ __launch_bounds__(256) void scan_a(int* __restrict__ data, int* __restrict__ partials, int m) {
    __shared__ int sdata[256];
    int base = blockIdx.x * 1024;
    int tid = threadIdx.x;
    int v[4]; int s = 0;
    #pragma unroll
    for (int i = 0; i < 4; ++i) { int idx = base + tid * 4 + i; v[i] = (idx < m) ? data[idx] : 0; s += v[i]; }
    sdata[tid] = s; __syncthreads();
    for (int off = 1; off < 256; off <<= 1) {
        int t = (tid >= off) ? sdata[tid - off] : 0; __syncthreads();
        sdata[tid] += t; __syncthreads();
    }
    int excl = sdata[tid] - s;
    if (tid == 255) partials[blockIdx.x] = sdata[255];
    int run = excl;
    #pragma unroll
    for (int i = 0; i < 4; ++i) { int idx = base + tid * 4 + i; if (idx < m) data[idx] = run; run += v[i]; }
}

__global__ __launch_bounds__(1024) void scan_b(int* __restrict__ partials, int nb) {
    __shared__ int sdata[1024];
    int tid = threadIdx.x;
    int v = (tid < nb) ? partials[tid] : 0;
    sdata[tid] = v; __syncthreads();
    for (int off = 1; off < 1024; off <<= 1) {
        int t = (tid >= off) ? sdata[tid - off] : 0; __syncthreads();
        sdata[tid] += t; __syncthreads();
    }
    if (tid < nb) partials[tid] = sdata[tid] - v;
}

// ---------------------------------------------------------------- P3: all 4 pipes, scatter into buckets (adds partials on the fly)
__global__ __launch_bounds__(256) void bucket_scatter_all(
    const int* __restrict__ k0, const int* __restrict__ k1,
    const int* __restrict__ k2, const int* __restrict__ k3,
    const int* __restrict__ pay0, const int* __restrict__ pay1,
    const int* __restrict__ scanned, const int* __restrict__ partials,
    unsigned* __restrict__ bucketed, int E, int chunk) {
    __shared__ unsigned cur[4][NBUCK];
    int tid = threadIdx.x;
    int blk = blockIdx.x;
    #pragma unroll
    for (int p = 0; p < 4; ++p) {
        int i0 = ((p << 9) + tid) * NB + blk;
        int i1 = ((p << 9) + tid + 256) * NB + blk;
        cur[p][tid]       = (unsigned)(scanned[i0] + partials[i0 >> 10]);
        cur[p][tid + 256] = (unsigned)(scanned[i1] + partials[i1 >> 10]);
    }
    __syncthreads();
    int base = blk * chunk;
    int end = min(base + chunk, E);
    const int* keys[4] = {k0, k1, k2, k3};
    const int* pays[4] = {pay0, pay1, nullptr, nullptr};
    #pragma unroll
    for (int p = 0; p < 4; ++p) {
        const int* kp = keys[p];
        const int* pp = pays[p];
        for (int i = base + tid; i < end; i += 256) {
            int k = kp[i];
            int b = k >> BSHIFT;
            unsigned pay = pp ? (unsigned)pp[i] : 0u;
            unsigned pos = atomicAdd(&cur[p][b], 1u);
            bucketed[pos] = ((unsigned)(k & 255) << 17) | pay;
        }
    }
}

// ---------------------------------------------------------------- P4: per bucket: degrees; dst pipes write PADDED csr (pad -> zero row n)
__global__ __launch_bounds__(256) void bucket_finalize(
    const unsigned* __restrict__ bucketed, const int* __restrict__ scanned,
    const int* __restrict__ partials,
    int* __restrict__ prow0, int* __restrict__ prow1,
    int* __restrict__ din0, int* __restrict__ din1,
    int* __restrict__ dout0, int* __restrict__ dout1,
    int* __restrict__ csr0, int* __restrict__ csr1, int n, int E) {
    __shared__ unsigned stage[STAGE_CAP];
    __shared__ int cnt[256];
    __shared__ int sd[256];
    __shared__ int pexcl[256];
    __shared__ int cur[256];
    int tid = threadIdx.x;
    int g = blockIdx.x;
    int p = g >> 9;
    int b = g & 511;
    int i0 = g * NB;
    int start = scanned[i0] + partials[i0 >> 10];
    int end;
    if (g == 4 * NBUCK - 1) end = 4 * E;
    else { int i1 = (g + 1) * NB; end = scanned[i1] + partials[i1 >> 10]; }
    if (end - start > STAGE_CAP) end = start + STAGE_CAP;
    int len = end - start;
    int node0 = b << BSHIFT;

    cnt[tid] = 0;
    __syncthreads();
    if (p < 2) {
        for (int i = tid; i < len; i += 256) {
            unsigned v = bucketed[start + i];
            stage[i] = v;
            atomicAdd(&cnt[v >> 17], 1);
        }
    } else {
        for (int i = tid; i < len; i += 256)
            atomicAdd(&cnt[bucketed[start + i] >> 17], 1);
    }
    __syncthreads();

    if (p >= 2) {                   // src-keyed: out-degrees only
        int* dout = (p == 2) ? dout0 : dout1;
        int node = node0 + tid;
        if (node < n) dout[node] = cnt[tid];
        return;
    }

    // dst-keyed: padded exclusive scan of ceil(cnt/16)*16
    int c = cnt[tid];
    int pc = (c + 15) & ~15;
    sd[tid] = pc;
    __syncthreads();
    for (int off = 1; off < 256; off <<= 1) {
        int t = (tid >= off) ? sd[tid - off] : 0; __syncthreads();
        sd[tid] += t; __syncthreads();
    }
    pexcl[tid] = sd[tid] - pc;
    cur[tid] = 0;
    __syncthreads();
    int ptot = sd[255];
    if (ptot > PCAP) ptot = PCAP;   // unreachable (+10 sigma)

    int* csr  = (p == 0) ? csr0  : csr1;
    int* prow = (p == 0) ? prow0 : prow1;
    int* din  = (p == 0) ? din0  : din1;
    int node = node0 + tid;
    if (node < n) { prow[node] = b * PCAP + pexcl[tid]; din[node] = c; }

    const int base = b * PCAP;
    for (int j = tid; j < ptot; j += 256) csr[base + j] = n;   // pad = zero row
    __syncthreads();
    for (int i = tid; i < len; i += 256) {
        unsigned w = stage[i];
        int nl = (int)(w >> 17);
        int pos = base + pexcl[nl] + atomicAdd(&cur[nl], 1);
        csr[pos] = (int)(w & 0x1FFFFu);
    }
}

// ---------------------------------------------------------------- swizzled B-fragment index for mfma_f32_16x16x32_bf16
__device__ __forceinline__ size_t bswz_idx(int k, int col) {
    int s = k >> 5, lh = (k >> 3) & 3, j = k & 7;
    int c = col >> 4, lc = col & 15;
    return ((((size_t)s * 8 + c) * 64 + (lh * 16 + lc)) * 8 + j);
}

// ---------------------------------------------------------------- weight_prep: blocks 0..128 = M=We@W1 fuse (+bias row);
// blocks 129..192 = swizzle_split of W2. One dispatch for all weight prep.
__global__ __launch_bounds__(256) void weight_prep(
    const float* __restrict__ We, const float* __restrict__ be,
    const float* __restrict__ W1, const float* __restrict__ W2,
    unsigned short* __restrict__ B1h, unsigned short* __restrict__ B1l,
    unsigned short* __restrict__ B2h, unsigned short* __restrict__ B2l,
    float* __restrict__ cv) {
    int tid = threadIdx.x;
    if (blockIdx.x >= 129) {
        int idx = (blockIdx.x - 129) * 256 + tid;
        if (idx >= 128 * 128) return;
        int k = idx >> 7, col = idx & 127;
        float v = W2[idx];
        unsigned short h = f2bf(v);
        unsigned short l = f2bf(v - bf2f(h));
        size_t o = bswz_idx(k, col);
        B2h[o] = h; B2l[o] = l;
        return;
    }
    __shared__ float w1[128][128];
    #pragma unroll
    for (int it = 0; it < 16; ++it) {
        int s = tid + it * 256;
        int r = s >> 5, c4 = (s & 31) << 2;
        *(float4*)&w1[r][c4] = *(const float4*)&W1[r * 128 + c4];
    }
    __syncthreads();
    int j = tid & 127;
    int half = tid >> 7;
    if (blockIdx.x == 128) {
        if (half) return;
        float sum = 0.f;
        for (int k = 0; k < 128; ++k) sum += be[k] * w1[k][j];
        cv[j] = sum;
        return;
    }
    int i = blockIdx.x * 2 + half;
    const float* arow = &We[i * 128];
    float sum = 0.f;
    for (int k = 0; k < 128; ++k) sum += arow[k] * w1[k][j];
    unsigned short h = f2bf(sum);
    unsigned short l = f2bf(sum - bf2f(h));
    size_t o = bswz_idx(i, j);
    B1h[o] = h; B1l[o] = l;
}

// ---------------------------------------------------------------- MFMA GEMM, LDS-staged B, double-buffered, 8-wave blocks
// (r12's best-measured structure: 16 rows/wave, 16KB slab per K-step, dbuf)
template <int K, bool AFP32>
__global__ __launch_bounds__(512) void gemm_lds(
    const void* __restrict__ X_,
    const unsigned short* __restrict__ Bh, const unsigned short* __restrict__ Bl,
    const float* __restrict__ cvec, const int* __restrict__ degs,
    unsigned short* __restrict__ T, int n) {
    constexpr int NS = K / 32;
    __shared__ __align__(16) char smem[2 * 16384];
    const int tid = threadIdx.x;
    const int wave = tid >> 6;
    const int lane = tid & 63;
    const int lr = lane & 15;
    const int lk = lane >> 4;
    const int row0 = blockIdx.x * 128 + wave * 16;
    const int grow = row0 + lr;
    const bool vr = grow < n;

    f32x4 acc[8];
    #pragma unroll
    for (int c = 0; c < 8; ++c) acc[c] = (f32x4)0.f;

    auto stage_slab = [&](int s, char* dst) {
        #pragma unroll
        for (int it = 0; it < 2; ++it) {
            int u = tid + it * 512;
            int f = u >> 6;
            int c = f >> 1, plane = f & 1;
            const unsigned short* srcArr = plane ? Bl : Bh;
            const char* g = (const char*)srcArr +
                ((size_t)(s * 512 + c * 64 + (u & 63)) * 16);
            gload_lds16(g, dst + u * 16);
        }
    };

    stage_slab(0, smem);

    const float* pxf = AFP32 ? (const float*)X_ + (size_t)grow * K + lk * 8 : nullptr;
    const unsigned short* pxb = AFP32 ? nullptr : (const unsigned short*)X_ + (size_t)grow * K + lk * 8;
    float4 a0 = make_float4(0.f, 0.f, 0.f, 0.f), a1 = a0;
    bf16x8 ab = (bf16x8)0;
    if (AFP32) {
        if (vr) { a0 = *(const float4*)pxf; a1 = *(const float4*)(pxf + 4); }
    } else {
        if (vr) ab = *(const bf16x8*)pxb;
    }

    #pragma unroll
    for (int s = 0; s < NS; ++s) {
        __syncthreads();   // slab s resident (compiler drains vmcnt here)
        if (s + 1 < NS) stage_slab(s + 1, smem + ((s + 1) & 1) * 16384);

        float4 n0 = make_float4(0.f, 0.f, 0.f, 0.f), n1 = n0;
        bf16x8 nb = (bf16x8)0;
        if (s + 1 < NS && vr) {
            if (AFP32) {
                n0 = *(const float4*)(pxf + (s + 1) * 32);
                n1 = *(const float4*)(pxf + (s + 1) * 32 + 4);
            } else {
                nb = *(const bf16x8*)(pxb + (s + 1) * 32);
            }
        }

        bf16x8 ah, al;
        if (AFP32) {
            float av[8] = {a0.x, a0.y, a0.z, a0.w, a1.x, a1.y, a1.z, a1.w};
            #pragma unroll
            for (int j = 0; j < 8; ++j) {
                unsigned short h = f2bf(av[j]);
                ah[j] = (short)h;
                al[j] = (short)f2bf(av[j] - bf2f(h));
            }
        } else {
            ah = ab;
        }

        const char* base = smem + (s & 1) * 16384 + lane * 16;
        #pragma unroll
        for (int c = 0; c < 8; ++c) {
            bf16x8 bh = *(const bf16x8*)(base + (c * 2) * 1024);
            bf16x8 bl = *(const bf16x8*)(base + (c * 2 + 1) * 1024);
            acc[c] = __builtin_amdgcn_mfma_f32_16x16x32_bf16(ah, bh, acc[c], 0, 0, 0);
            acc[c] = __builtin_amdgcn_mfma_f32_16x16x32_bf16(ah, bl, acc[c], 0, 0, 0);
            if (AFP32)
                acc[c] = __builtin_amdgcn_mfma_f32_16x16x32_bf16(al, bh, acc[c], 0, 0, 0);
        }
        a0 = n0; a1 = n1; ab = nb;
    }

    // C/D: col = lane&15, row = lk*4 + r
    #pragma unroll
    for (int r = 0; r < 4; ++r) {
        int orow = row0 + lk * 4 + r;
        if (orow >= n) continue;
        float norm = rsqrtf(fmaxf((float)degs[orow], 1.0f));
        #pragma unroll
        for (int c = 0; c < 8; ++c) {
            float v = acc[c][r];
            if (cvec) v += cvec[c * 16 + lr];
            T[(size_t)orow * 128 + c * 16 + lr] = f2bf(v * norm);
        }
    }
}

// ---------------------------------------------------------------- aggregate: padded CSR, zero tail -> always 8 gathers in flight
template <bool OUT_BF16>
__global__ __launch_bounds__(256) void aggregate(
    const unsigned short* __restrict__ T, const int* __restrict__ prow,
    const int* __restrict__ din, const int* __restrict__ csr,
    const float* __restrict__ bias, void* __restrict__ out_, int n) {
    const int wave = threadIdx.x >> 6;
    const int lane = threadIdx.x & 63;
    const int half = lane >> 5;
    const int l32 = lane & 31;
    const int node = blockIdx.x * 4 + wave;
    if (node >= n) return;
    const int beg = prow[node];
    const int d = din[node];
    const int plen = (d + 15) & ~15;
    float a0 = 0.f, a1 = 0.f, a2 = 0.f, a3 = 0.f;
    for (int e = beg; e < beg + plen; e += 16) {
        int sidx[8];
        #pragma unroll
        for (int j = 0; j < 8; ++j) sidx[j] = csr[e + j * 2 + half];
        #pragma unroll
        for (int j = 0; j < 8; ++j) {
            uint2 u = *(const uint2*)&T[(size_t)sidx[j] * 128 + l32 * 4];
            a0 += __uint_as_float(u.x << 16);
            a1 += __uint_as_float(u.x & 0xffff0000u);
            a2 += __uint_as_float(u.y << 16);
            a3 += __uint_as_float(u.y & 0xffff0000u);
        }
    }
    a0 += __shfl_xor(a0, 32);
    a1 += __shfl_xor(a1, 32);
    a2 += __shfl_xor(a2, 32);
    a3 += __shfl_xor(a3, 32);
    if (half == 0) {
        float norm = rsqrtf(fmaxf((float)d, 1.0f));
        float4 bv = *(const float4*)&bias[l32 * 4];
        float o0 = fmaxf(a0 * norm + bv.x, 0.f);
        float o1 = fmaxf(a1 * norm + bv.y, 0.f);
        float o2 = fmaxf(a2 * norm + bv.z, 0.f);
        float o3 = fmaxf(a3 * norm + bv.w, 0.f);
        if (OUT_BF16) {
            unsigned w0 = (unsigned)f2bf(o0) | ((unsigned)f2bf(o1) << 16);
            unsigned w1 = (unsigned)f2bf(o2) | ((unsigned)f2bf(o3) << 16);
            uint2* dst = (uint2*)((unsigned short*)out_ + (size_t)node * 128 + l32 * 4);
            *dst = make_uint2(w0, w1);
        } else {
            float4* dst = (float4*)((float*)out_ + (size_t)node * 128 + l32 * 4);
            *dst = make_float4(o0, o1, o2, o3);
        }
    }
}

// ---------------------------------------------------------------- launch
extern "C" void kernel_launch(void* const* d_in, const int* in_sizes, int n_in,
                              void* d_out, int out_size, void* d_ws, size_t ws_size,
                              hipStream_t stream) {
    const float* x   = (const float*)d_in[0];
    const float* We  = (const float*)d_in[1];
    const float* be  = (const float*)d_in[2];
    const float* W1  = (const float*)d_in[3];
    const float* b1  = (const float*)d_in[4];
    const float* W2  = (const float*)d_in[5];
    const float* b2  = (const float*)d_in[6];
    const int* src0  = (const int*)d_in[7];
    const int* dst0  = (const int*)d_in[8];
    const int* src1  = (const int*)d_in[9];
    const int* dst1  = (const int*)d_in[10];
    float* out = (float*)d_out;

    const int n = in_sizes[0] / 256;   // 100000
    const int E = in_sizes[7];         // 1600000
    const int chunk = (E + NB - 1) / NB;

    char* p = (char*)d_ws;
    auto carve = [&](size_t bytes) -> void* {
        void* r = (void*)p;
        p += (bytes + 511) & ~(size_t)511;
        return r;
    };
    unsigned short* t        = (unsigned short*)carve(((size_t)n + 1) * HID * 2);  // [(n+1)][128] bf16, row n = zeros
    unsigned*       bucketed = (unsigned*)carve((size_t)4 * E * 4);                // dead after finalize -> h1 overlay
    int*            counts   = (int*)carve((size_t)M4 * 4);
    int*            partials = (int*)carve(1024 * 4);
    int*            csr0     = (int*)carve((size_t)NBUCK * PCAP * 4);   // 14.7 MB
    int*            csr1     = (int*)carve((size_t)NBUCK * PCAP * 4);
    int*            prow0    = (int*)carve((size_t)n * 4);
    int*            prow1    = (int*)carve((size_t)n * 4);
    int*            din0     = (int*)carve((size_t)n * 4);
    int*            din1     = (int*)carve((size_t)n * 4);
    int*            dout0    = (int*)carve((size_t)n * 4);
    int*            dout1    = (int*)carve((size_t)n * 4);
    unsigned short* B1h      = (unsigned short*)carve(256 * HID * 2);
    unsigned short* B1l      = (unsigned short*)carve(256 * HID * 2);
    unsigned short* B2h      = (unsigned short*)carve(128 * HID * 2);
    unsigned short* B2l      = (unsigned short*)carve(128 * HID * 2);
    float*          cv       = (float*)carve(HID * 4);

    unsigned short* h1 = (unsigned short*)bucketed;   // bucketed dead after finalize; exact 25.6 MB fit

    const int gGemm  = (n + 127) / 128;      // 782 blocks, 8 waves, 128 rows each
    const int gAggN  = (n + 3) / 4;
    const int gScanA = (M4 + 1023) / 1024;   // 1024

    // zero pad-row of t (gathers for padded csr entries land here, stays L2-hot)
    hipMemsetAsync(t + (size_t)n * HID, 0, HID * 2, stream);

    // --- graph build (zero global atomics) ---
    bucket_count_all<<<NB, 256, 0, stream>>>(dst0, dst1, src0, src1, counts, E, chunk);
    scan_a<<<gScanA, 256, 0, stream>>>(counts, partials, M4);
    scan_b<<<1, 1024, 0, stream>>>(partials, gScanA);
    bucket_scatter_all<<<NB, 256, 0, stream>>>(dst0, dst1, src0, src1, src0, src1,
                                               counts, partials, bucketed, E, chunk);
    bucket_finalize<<<4 * NBUCK, 256, 0, stream>>>(bucketed, counts, partials, prow0, prow1,
                                                   din0, din1, dout0, dout1, csr0, csr1, n, E);

    // --- weights (single dispatch) ---
    weight_prep<<<193, 256, 0, stream>>>(We, be, W1, W2, B1h, B1l, B2h, B2l, cv);

    // --- network ---
    gemm_lds<256, true><<<gGemm, 512, 0, stream>>>((const void*)x, B1h, B1l, cv, dout0, t, n);
    aggregate<true><<<gAggN, 256, 0, stream>>>(t, prow0, din0, csr0, b1, (void*)h1, n);
    gemm_lds<128, false><<<gGemm, 512, 0, stream>>>((const void*)h1, B2h, B2l, nullptr, dout1, t, n);
    aggregate<false><<<gAggN, 256, 0, stream>>>(t, prow1, din1, csr1, b2, (void*)out, n);
}

// Round 18
// 298.891 us; speedup vs baseline: 1.3577x; 1.0033x over previous
//
#include <hip/hip_runtime.h>

#define HID 128
#define NBUCK 512          // 2^9 buckets, 256 nodes each
#define BSHIFT 8
#define NB 512             // chunk blocks per pipeline
#define M4 (4 * NBUCK * NB)
#define STAGE_CAP 8192     // real edges per bucket: mean 4096, +64 sigma
#define PCAP 7168          // padded csr slots per bucket: mean 5888, +10 sigma

typedef __attribute__((ext_vector_type(8))) short bf16x8;
typedef __attribute__((ext_vector_type(4))) float f32x4;

__device__ __forceinline__ unsigned short f2bf(float f) {   // RNE
    union { float f; unsigned u; } v; v.f = f;
    unsigned r = v.u + 0x7fff + ((v.u >> 16) & 1);
    return (unsigned short)(r >> 16);
}
__device__ __forceinline__ float bf2f(unsigned short b) {
    union { float f; unsigned u; } v; v.u = ((unsigned)b) << 16;
    return v.f;
}

// async global->LDS, 16B per lane (global_load_lds_dwordx4)
__device__ __forceinline__ void gload_lds16(const void* g, void* l) {
    __builtin_amdgcn_global_load_lds(
        (const __attribute__((address_space(1))) void*)g,
        (__attribute__((address_space(3))) void*)l, 16, 0, 0);
}

// ---------------------------------------------------------------- P1: all 4 pipes, per-(bucket, block) counts
__global__ __launch_bounds__(256) void bucket_count_all(
    const int* __restrict__ k0, const int* __restrict__ k1,
    const int* __restrict__ k2, const int* __restrict__ k3,
    int* __restrict__ counts, int E, int chunk) {
    __shared__ int h[4][NBUCK];
    int tid = threadIdx.x;
    #pragma unroll
    for (int j = 0; j < 8; ++j) ((int*)h)[tid + j * 256] = 0;
    __syncthreads();
    int base = blockIdx.x * chunk;
    int end = min(base + chunk, E);
    const int* keys[4] = {k0, k1, k2, k3};
    #pragma unroll
    for (int p = 0; p < 4; ++p) {
        const int* kp = keys[p];
        for (int i = base + tid; i < end; i += 256)
            atomicAdd(&h[p][kp[i] >> BSHIFT], 1);
    }
    __syncthreads();
    #pragma unroll
    for (int p = 0; p < 4; ++p) {
        counts[((p << 9) + tid) * NB + blockIdx.x] = h[p][tid];
        counts[((p << 9) + tid + 256) * NB + blockIdx.x] = h[p][tid + 256];
    }
}

// ---------------------------------------------------------------- scan (2 kernels; scan_c folded into consumers)
__global__ __launch_bounds__(256) void scan_a(int* __restrict__ data, int* __restrict__ partials, int m) {
    __shared__ int sdata[256];
    int base = blockIdx.x * 1024;
    int tid = threadIdx.x;
    int v[4]; int s = 0;
    #pragma unroll
    for (int i = 0; i < 4; ++i) { int idx = base + tid * 4 + i; v[i] = (idx < m) ? data[idx] : 0; s += v[i]; }
    sdata[tid] = s; __syncthreads();
    for (int off = 1; off < 256; off <<= 1) {
        int t = (tid >= off) ? sdata[tid - off] : 0; __syncthreads();
        sdata[tid] += t; __syncthreads();
    }
    int excl = sdata[tid] - s;
    if (tid == 255) partials[blockIdx.x] = sdata[255];
    int run = excl;
    #pragma unroll
    for (int i = 0; i < 4; ++i) { int idx = base + tid * 4 + i; if (idx < m) data[idx] = run; run += v[i]; }
}

__global__ __launch_bounds__(1024) void scan_b(int* __restrict__ partials, int nb) {
    __shared__ int sdata[1024];
    int tid = threadIdx.x;
    int v = (tid < nb) ? partials[tid] : 0;
    sdata[tid] = v; __syncthreads();
    for (int off = 1; off < 1024; off <<= 1) {
        int t = (tid >= off) ? sdata[tid - off] : 0; __syncthreads();
        sdata[tid] += t; __syncthreads();
    }
    if (tid < nb) partials[tid] = sdata[tid] - v;
}

// ---------------------------------------------------------------- P3: all 4 pipes, scatter into buckets (adds partials on the fly)
__global__ __launch_bounds__(256) void bucket_scatter_all(
    const int* __restrict__ k0, const int* __restrict__ k1,
    const int* __restrict__ k2, const int* __restrict__ k3,
    const int* __restrict__ pay0, const int* __restrict__ pay1,
    const int* __restrict__ scanned, const int* __restrict__ partials,
    unsigned* __restrict__ bucketed, int E, int chunk) {
    __shared__ unsigned cur[4][NBUCK];
    int tid = threadIdx.x;
    int blk = blockIdx.x;
    #pragma unroll
    for (int p = 0; p < 4; ++p) {
        int i0 = ((p << 9) + tid) * NB + blk;
        int i1 = ((p << 9) + tid + 256) * NB + blk;
        cur[p][tid]       = (unsigned)(scanned[i0] + partials[i0 >> 10]);
        cur[p][tid + 256] = (unsigned)(scanned[i1] + partials[i1 >> 10]);
    }
    __syncthreads();
    int base = blk * chunk;
    int end = min(base + chunk, E);
    const int* keys[4] = {k0, k1, k2, k3};
    const int* pays[4] = {pay0, pay1, nullptr, nullptr};
    #pragma unroll
    for (int p = 0; p < 4; ++p) {
        const int* kp = keys[p];
        const int* pp = pays[p];
        for (int i = base + tid; i < end; i += 256) {
            int k = kp[i];
            int b = k >> BSHIFT;
            unsigned pay = pp ? (unsigned)pp[i] : 0u;
            unsigned pos = atomicAdd(&cur[p][b], 1u);
            bucketed[pos] = ((unsigned)(k & 255) << 17) | pay;
        }
    }
}

// ---------------------------------------------------------------- P4: per bucket: degrees; dst pipes write PADDED csr (pad -> zero row n)
__global__ __launch_bounds__(256) void bucket_finalize(
    const unsigned* __restrict__ bucketed, const int* __restrict__ scanned,
    const int* __restrict__ partials,
    int* __restrict__ prow0, int* __restrict__ prow1,
    int* __restrict__ din0, int* __restrict__ din1,
    int* __restrict__ dout0, int* __restrict__ dout1,
    int* __restrict__ csr0, int* __restrict__ csr1, int n, int E) {
    __shared__ unsigned stage[STAGE_CAP];
    __shared__ int cnt[256];
    __shared__ int sd[256];
    __shared__ int pexcl[256];
    __shared__ int cur[256];
    int tid = threadIdx.x;
    int g = blockIdx.x;
    int p = g >> 9;
    int b = g & 511;
    int i0 = g * NB;
    int start = scanned[i0] + partials[i0 >> 10];
    int end;
    if (g == 4 * NBUCK - 1) end = 4 * E;
    else { int i1 = (g + 1) * NB; end = scanned[i1] + partials[i1 >> 10]; }
    if (end - start > STAGE_CAP) end = start + STAGE_CAP;
    int len = end - start;
    int node0 = b << BSHIFT;

    cnt[tid] = 0;
    __syncthreads();
    if (p < 2) {
        for (int i = tid; i < len; i += 256) {
            unsigned v = bucketed[start + i];
            stage[i] = v;
            atomicAdd(&cnt[v >> 17], 1);
        }
    } else {
        for (int i = tid; i < len; i += 256)
            atomicAdd(&cnt[bucketed[start + i] >> 17], 1);
    }
    __syncthreads();

    if (p >= 2) {                   // src-keyed: out-degrees only
        int* dout = (p == 2) ? dout0 : dout1;
        int node = node0 + tid;
        if (node < n) dout[node] = cnt[tid];
        return;
    }

    // dst-keyed: padded exclusive scan of ceil(cnt/16)*16
    int c = cnt[tid];
    int pc = (c + 15) & ~15;
    sd[tid] = pc;
    __syncthreads();
    for (int off = 1; off < 256; off <<= 1) {
        int t = (tid >= off) ? sd[tid - off] : 0; __syncthreads();
        sd[tid] += t; __syncthreads();
    }
    pexcl[tid] = sd[tid] - pc;
    cur[tid] = 0;
    __syncthreads();
    int ptot = sd[255];
    if (ptot > PCAP) ptot = PCAP;   // unreachable (+10 sigma)

    int* csr  = (p == 0) ? csr0  : csr1;
    int* prow = (p == 0) ? prow0 : prow1;
    int* din  = (p == 0) ? din0  : din1;
    int node = node0 + tid;
    if (node < n) { prow[node] = b * PCAP + pexcl[tid]; din[node] = c; }

    const int base = b * PCAP;
    for (int j = tid; j < ptot; j += 256) csr[base + j] = n;   // pad = zero row
    __syncthreads();
    for (int i = tid; i < len; i += 256) {
        unsigned w = stage[i];
        int nl = (int)(w >> 17);
        int pos = base + pexcl[nl] + atomicAdd(&cur[nl], 1);
        csr[pos] = (int)(w & 0x1FFFFu);
    }
}

// ---------------------------------------------------------------- swizzled B-fragment index for mfma_f32_16x16x32_bf16
__device__ __forceinline__ size_t bswz_idx(int k, int col) {
    int s = k >> 5, lh = (k >> 3) & 3, j = k & 7;
    int c = col >> 4, lc = col & 15;
    return ((((size_t)s * 8 + c) * 64 + (lh * 16 + lc)) * 8 + j);
}

// ---------------------------------------------------------------- weight_prep: blocks 0..128 = M=We@W1 fuse (+bias row);
// blocks 129..192 = swizzle_split of W2. One dispatch for all weight prep.
__global__ __launch_bounds__(256) void weight_prep(
    const float* __restrict__ We, const float* __restrict__ be,
    const float* __restrict__ W1, const float* __restrict__ W2,
    unsigned short* __restrict__ B1h, unsigned short* __restrict__ B1l,
    unsigned short* __restrict__ B2h, unsigned short* __restrict__ B2l,
    float* __restrict__ cv) {
    int tid = threadIdx.x;
    if (blockIdx.x >= 129) {
        int idx = (blockIdx.x - 129) * 256 + tid;
        if (idx >= 128 * 128) return;
        int k = idx >> 7, col = idx & 127;
        float v = W2[idx];
        unsigned short h = f2bf(v);
        unsigned short l = f2bf(v - bf2f(h));
        size_t o = bswz_idx(k, col);
        B2h[o] = h; B2l[o] = l;
        return;
    }
    __shared__ float w1[128][128];
    #pragma unroll
    for (int it = 0; it < 16; ++it) {
        int s = tid + it * 256;
        int r = s >> 5, c4 = (s & 31) << 2;
        *(float4*)&w1[r][c4] = *(const float4*)&W1[r * 128 + c4];
    }
    __syncthreads();
    int j = tid & 127;
    int half = tid >> 7;
    if (blockIdx.x == 128) {
        if (half) return;
        float sum = 0.f;
        for (int k = 0; k < 128; ++k) sum += be[k] * w1[k][j];
        cv[j] = sum;
        return;
    }
    int i = blockIdx.x * 2 + half;
    const float* arow = &We[i * 128];
    float sum = 0.f;
    for (int k = 0; k < 128; ++k) sum += arow[k] * w1[k][j];
    unsigned short h = f2bf(sum);
    unsigned short l = f2bf(sum - bf2f(h));
    size_t o = bswz_idx(i, j);
    B1h[o] = h; B1l[o] = l;
}

// ---------------------------------------------------------------- MFMA GEMM, LDS-staged B, double-buffered, 8-wave blocks
// (r12 structure) + NEW: epilogue LDS-transpose -> coalesced uint4 C-stores
// (replaces the 32 scalar 2B stores/thread shared by ALL previous variants).
template <int K, bool AFP32>
__global__ __launch_bounds__(512) void gemm_lds(
    const void* __restrict__ X_,
    const unsigned short* __restrict__ Bh, const unsigned short* __restrict__ Bl,
    const float* __restrict__ cvec, const int* __restrict__ degs,
    unsigned short* __restrict__ T, int n) {
    constexpr int NS = K / 32;
    // 2x16KB B slabs for the K-loop; >=34816B so epilogue tiles (8 x 16x136 ushort) fit
    __shared__ __align__(16) char smem[35840];
    const int tid = threadIdx.x;
    const int wave = tid >> 6;
    const int lane = tid & 63;
    const int lr = lane & 15;
    const int lk = lane >> 4;
    const int row0 = blockIdx.x * 128 + wave * 16;
    const int grow = row0 + lr;
    const bool vr = grow < n;

    f32x4 acc[8];
    #pragma unroll
    for (int c = 0; c < 8; ++c) acc[c] = (f32x4)0.f;

    auto stage_slab = [&](int s, char* dst) {
        #pragma unroll
        for (int it = 0; it < 2; ++it) {
            int u = tid + it * 512;
            int f = u >> 6;
            int c = f >> 1, plane = f & 1;
            const unsigned short* srcArr = plane ? Bl : Bh;
            const char* g = (const char*)srcArr +
                ((size_t)(s * 512 + c * 64 + (u & 63)) * 16);
            gload_lds16(g, dst + u * 16);
        }
    };

    stage_slab(0, smem);

    const float* pxf = AFP32 ? (const float*)X_ + (size_t)grow * K + lk * 8 : nullptr;
    const unsigned short* pxb = AFP32 ? nullptr : (const unsigned short*)X_ + (size_t)grow * K + lk * 8;
    float4 a0 = make_float4(0.f, 0.f, 0.f, 0.f), a1 = a0;
    bf16x8 ab = (bf16x8)0;
    if (AFP32) {
        if (vr) { a0 = *(const float4*)pxf; a1 = *(const float4*)(pxf + 4); }
    } else {
        if (vr) ab = *(const bf16x8*)pxb;
    }

    #pragma unroll
    for (int s = 0; s < NS; ++s) {
        __syncthreads();   // slab s resident (compiler drains vmcnt here)
        if (s + 1 < NS) stage_slab(s + 1, smem + ((s + 1) & 1) * 16384);

        float4 n0 = make_float4(0.f, 0.f, 0.f, 0.f), n1 = n0;
        bf16x8 nb = (bf16x8)0;
        if (s + 1 < NS && vr) {
            if (AFP32) {
                n0 = *(const float4*)(pxf + (s + 1) * 32);
                n1 = *(const float4*)(pxf + (s + 1) * 32 + 4);
            } else {
                nb = *(const bf16x8*)(pxb + (s + 1) * 32);
            }
        }

        bf16x8 ah, al;
        if (AFP32) {
            float av[8] = {a0.x, a0.y, a0.z, a0.w, a1.x, a1.y, a1.z, a1.w};
            #pragma unroll
            for (int j = 0; j < 8; ++j) {
                unsigned short h = f2bf(av[j]);
                ah[j] = (short)h;
                al[j] = (short)f2bf(av[j] - bf2f(h));
            }
        } else {
            ah = ab;
        }

        const char* base = smem + (s & 1) * 16384 + lane * 16;
        #pragma unroll
        for (int c = 0; c < 8; ++c) {
            bf16x8 bh = *(const bf16x8*)(base + (c * 2) * 1024);
            bf16x8 bl = *(const bf16x8*)(base + (c * 2 + 1) * 1024);
            acc[c] = __builtin_amdgcn_mfma_f32_16x16x32_bf16(ah, bh, acc[c], 0, 0, 0);
            acc[c] = __builtin_amdgcn_mfma_f32_16x16x32_bf16(ah, bl, acc[c], 0, 0, 0);
            if (AFP32)
                acc[c] = __builtin_amdgcn_mfma_f32_16x16x32_bf16(al, bh, acc[c], 0, 0, 0);
        }
        a0 = n0; a1 = n1; ab = nb;
    }

    // ---- epilogue: per-wave LDS tile [16][136] -> coalesced uint4 stores ----
    __syncthreads();   // all waves done reading B slabs; safe to reuse smem
    unsigned short* lt = (unsigned short*)smem + wave * (16 * 136);
    #pragma unroll
    for (int r = 0; r < 4; ++r) {
        int orow = row0 + lk * 4 + r;
        int orc = (orow < n) ? orow : (n - 1);
        float norm = rsqrtf(fmaxf((float)degs[orc], 1.0f));
        #pragma unroll
        for (int c = 0; c < 8; ++c) {
            float v = acc[c][r];
            if (cvec) v += cvec[c * 16 + lr];
            lt[(lk * 4 + r) * 136 + c * 16 + lr] = f2bf(v * norm);
        }
    }
    // wave reads back ITS OWN tile (no cross-wave dependency; lgkmcnt auto)
    #pragma unroll
    for (int j = 0; j < 4; ++j) {
        int row = j * 4 + lk;              // 0..15
        int orow = row0 + row;
        if (orow < n) {
            uint4 v = *(const uint4*)(lt + row * 136 + lr * 8);
            *(uint4*)(T + (size_t)orow * 128 + lr * 8) = v;
        }
    }
}

// ---------------------------------------------------------------- aggregate: padded CSR, zero tail -> always 8 gathers in flight
template <bool OUT_BF16>
__global__ __launch_bounds__(256) void aggregate(
    const unsigned short* __restrict__ T, const int* __restrict__ prow,
    const int* __restrict__ din, const int* __restrict__ csr,
    const float* __restrict__ bias, void* __restrict__ out_, int n) {
    const int wave = threadIdx.x >> 6;
    const int lane = threadIdx.x & 63;
    const int half = lane >> 5;
    const int l32 = lane & 31;
    const int node = blockIdx.x * 4 + wave;
    if (node >= n) return;
    const int beg = prow[node];
    const int d = din[node];
    const int plen = (d + 15) & ~15;
    float a0 = 0.f, a1 = 0.f, a2 = 0.f, a3 = 0.f;
    for (int e = beg; e < beg + plen; e += 16) {
        int sidx[8];
        #pragma unroll
        for (int j = 0; j < 8; ++j) sidx[j] = csr[e + j * 2 + half];
        #pragma unroll
        for (int j = 0; j < 8; ++j) {
            uint2 u = *(const uint2*)&T[(size_t)sidx[j] * 128 + l32 * 4];
            a0 += __uint_as_float(u.x << 16);
            a1 += __uint_as_float(u.x & 0xffff0000u);
            a2 += __uint_as_float(u.y << 16);
            a3 += __uint_as_float(u.y & 0xffff0000u);
        }
    }
    a0 += __shfl_xor(a0, 32);
    a1 += __shfl_xor(a1, 32);
    a2 += __shfl_xor(a2, 32);
    a3 += __shfl_xor(a3, 32);
    if (half == 0) {
        float norm = rsqrtf(fmaxf((float)d, 1.0f));
        float4 bv = *(const float4*)&bias[l32 * 4];
        float o0 = fmaxf(a0 * norm + bv.x, 0.f);
        float o1 = fmaxf(a1 * norm + bv.y, 0.f);
        float o2 = fmaxf(a2 * norm + bv.z, 0.f);
        float o3 = fmaxf(a3 * norm + bv.w, 0.f);
        if (OUT_BF16) {
            unsigned w0 = (unsigned)f2bf(o0) | ((unsigned)f2bf(o1) << 16);
            unsigned w1 = (unsigned)f2bf(o2) | ((unsigned)f2bf(o3) << 16);
            uint2* dst = (uint2*)((unsigned short*)out_ + (size_t)node * 128 + l32 * 4);
            *dst = make_uint2(w0, w1);
        } else {
            float4* dst = (float4*)((float*)out_ + (size_t)node * 128 + l32 * 4);
            *dst = make_float4(o0, o1, o2, o3);
        }
    }
}

// ---------------------------------------------------------------- launch
extern "C" void kernel_launch(void* const* d_in, const int* in_sizes, int n_in,
                              void* d_out, int out_size, void* d_ws, size_t ws_size,
                              hipStream_t stream) {
    const float* x   = (const float*)d_in[0];
    const float* We  = (const float*)d_in[1];
    const float* be  = (const float*)d_in[2];
    const float* W1  = (const float*)d_in[3];
    const float* b1  = (const float*)d_in[4];
    const float* W2  = (const float*)d_in[5];
    const float* b2  = (const float*)d_in[6];
    const int* src0  = (const int*)d_in[7];
    const int* dst0  = (const int*)d_in[8];
    const int* src1  = (const int*)d_in[9];
    const int* dst1  = (const int*)d_in[10];
    float* out = (float*)d_out;

    const int n = in_sizes[0] / 256;   // 100000
    const int E = in_sizes[7];         // 1600000
    const int chunk = (E + NB - 1) / NB;

    char* p = (char*)d_ws;
    auto carve = [&](size_t bytes) -> void* {
        void* r = (void*)p;
        p += (bytes + 511) & ~(size_t)511;
        return r;
    };
    unsigned short* t        = (unsigned short*)carve(((size_t)n + 1) * HID * 2);  // [(n+1)][128] bf16, row n = zeros
    unsigned*       bucketed = (unsigned*)carve((size_t)4 * E * 4);                // dead after finalize -> h1 overlay
    int*            counts   = (int*)carve((size_t)M4 * 4);
    int*            partials = (int*)carve(1024 * 4);
    int*            csr0     = (int*)carve((size_t)NBUCK * PCAP * 4);   // 14.7 MB
    int*            csr1     = (int*)carve((size_t)NBUCK * PCAP * 4);
    int*            prow0    = (int*)carve((size_t)n * 4);
    int*            prow1    = (int*)carve((size_t)n * 4);
    int*            din0     = (int*)carve((size_t)n * 4);
    int*            din1     = (int*)carve((size_t)n * 4);
    int*            dout0    = (int*)carve((size_t)n * 4);
    int*            dout1    = (int*)carve((size_t)n * 4);
    unsigned short* B1h      = (unsigned short*)carve(256 * HID * 2);
    unsigned short* B1l      = (unsigned short*)carve(256 * HID * 2);
    unsigned short* B2h      = (unsigned short*)carve(128 * HID * 2);
    unsigned short* B2l      = (unsigned short*)carve(128 * HID * 2);
    float*          cv       = (float*)carve(HID * 4);

    unsigned short* h1 = (unsigned short*)bucketed;   // bucketed dead after finalize; exact 25.6 MB fit

    const int gGemm  = (n + 127) / 128;      // 782 blocks, 8 waves, 128 rows each
    const int gAggN  = (n + 3) / 4;
    const int gScanA = (M4 + 1023) / 1024;   // 1024

    // zero pad-row of t (gathers for padded csr entries land here, stays L2-hot)
    hipMemsetAsync(t + (size_t)n * HID, 0, HID * 2, stream);

    // --- graph build (zero global atomics) ---
    bucket_count_all<<<NB, 256, 0, stream>>>(dst0, dst1, src0, src1, counts, E, chunk);
    scan_a<<<gScanA, 256, 0, stream>>>(counts, partials, M4);
    scan_b<<<1, 1024, 0, stream>>>(partials, gScanA);
    bucket_scatter_all<<<NB, 256, 0, stream>>>(dst0, dst1, src0, src1, src0, src1,
                                               counts, partials, bucketed, E, chunk);
    bucket_finalize<<<4 * NBUCK, 256, 0, stream>>>(bucketed, counts, partials, prow0, prow1,
                                                   din0, din1, dout0, dout1, csr0, csr1, n, E);

    // --- weights (single dispatch) ---
    weight_prep<<<193, 256, 0, stream>>>(We, be, W1, W2, B1h, B1l, B2h, B2l, cv);

    // --- network ---
    gemm_lds<256, true><<<gGemm, 512, 0, stream>>>((const void*)x, B1h, B1l, cv, dout0, t, n);
    aggregate<true><<<gAggN, 256, 0, stream>>>(t, prow0, din0, csr0, b1, (void*)h1, n);
    gemm_lds<128, false><<<gGemm, 512, 0, stream>>>((const void*)h1, B2h, B2l, nullptr, dout1, t, n);
    aggregate<false><<<gAggN, 256, 0, stream>>>(t, prow1, din1, csr1, b2, (void*)out, n);
}